// Round 19
// baseline (198.977 us; speedup 1.0000x reference)
//
#include <hip/hip_runtime.h>

#define T_STEPS 512
#define HID 128
#define ROWS 16   // batch rows per block -> 64 blocks

typedef short bf16x8 __attribute__((ext_vector_type(8)));   // MFMA A/B frag
typedef float f32x4  __attribute__((ext_vector_type(4)));   // MFMA C/D frag
typedef unsigned int u32;
typedef u32 u32x4 __attribute__((ext_vector_type(4)));

// R18 (164.5us) + ONE change: the 9-deep same-acc MFMA chain (R18 counters:
// ~30cyc per dependent MFMA = 270cyc critical path) is split into TWO
// parallel chains (bias+WH0..3 -> acc0, WL0..3 -> acc1, both starting from
// literal-zero C) + one f32x4 add. Dep depth 5/4 -> ~150cyc MFMA path.

__device__ __forceinline__ u32 cvt_pk_bf16(float s0, float s1) {
    u32 d;  // d.lo = bf16(s0), d.hi = bf16(s1)
    asm("v_cvt_pk_bf16_f32 %0, %1, %2" : "=v"(d) : "v"(s0), "v"(s1));
    return d;
}
__device__ __forceinline__ bf16x8 frag_from(u32 a, u32 b, u32 c, u32 d) {
    u32x4 t = {a, b, c, d};
    return __builtin_bit_cast(bf16x8, t);
}
// tanh(a) = 1 - 2/(exp2(2a*log2e)+1); saturates correctly at +-inf
__device__ __forceinline__ float tanh_fast(float a) {
    const float e  = __builtin_amdgcn_exp2f(a * 2.885390081777926816f);
    const float rc = __builtin_amdgcn_rcpf(e + 1.0f);
    return fmaf(-2.0f, rc, 1.0f);
}

// split 8 f32 into hi/lo bf16 frags (W ~= WH + WL, residual ~2^-18 rel)
#define SPLIT8(HI, LO, fa, fb) do {                                           \
    u32 h0_ = cvt_pk_bf16(fa.x,fa.y), h1_ = cvt_pk_bf16(fa.z,fa.w);           \
    u32 h2_ = cvt_pk_bf16(fb.x,fb.y), h3_ = cvt_pk_bf16(fb.z,fb.w);           \
    float l0_ = fa.x - __uint_as_float(h0_ << 16);                            \
    float l1_ = fa.y - __uint_as_float(h0_ & 0xffff0000u);                    \
    float l2_ = fa.z - __uint_as_float(h1_ << 16);                            \
    float l3_ = fa.w - __uint_as_float(h1_ & 0xffff0000u);                    \
    float l4_ = fb.x - __uint_as_float(h2_ << 16);                            \
    float l5_ = fb.y - __uint_as_float(h2_ & 0xffff0000u);                    \
    float l6_ = fb.z - __uint_as_float(h3_ << 16);                            \
    float l7_ = fb.w - __uint_as_float(h3_ & 0xffff0000u);                    \
    u32 g0_ = cvt_pk_bf16(l0_,l1_), g1_ = cvt_pk_bf16(l2_,l3_);               \
    u32 g2_ = cvt_pk_bf16(l4_,l5_), g3_ = cvt_pk_bf16(l6_,l7_);               \
    HI = frag_from(h0_,h1_,h2_,h3_); LO = frag_from(g0_,g1_,g2_,g3_);         \
} while (0)

#define MFMA(ACC, A, B) \
    ACC = __builtin_amdgcn_mfma_f32_16x16x32_bf16(A, B, ACC, 0, 0, 0);

// LDS: h buf0 @0, h buf1 @4096 (slot-major, R16-verified); red @8192
#define LDS_BYTES (8192 + 512)

__global__ __launch_bounds__(512, 1)
__attribute__((amdgpu_waves_per_eu(2, 2)))
void rnn_diet2_kernel(const float* __restrict__ x,
                      const float* __restrict__ W_ih,
                      const float* __restrict__ W_hh,
                      const float* __restrict__ b_ih,
                      const float* __restrict__ b_hh,
                      const float* __restrict__ W_out,
                      const float* __restrict__ b_out,
                      float* __restrict__ y)
{
    __shared__ __align__(16) char lds[LDS_BYTES];

    const int tid = threadIdx.x;
    const int w   = tid >> 6;        // wave 0..7: j-tile [16w, 16w+16)
    const int l   = tid & 63;
    const int q   = l >> 4;          // lane quarter (k-group / C row group)
    const int r   = l & 15;          // batch row (A row m / B col n / C col n)
    const int b0  = blockIdx.x * ROWS;

    // ---- zero h buf0 (4 KB, 512 threads x 8 B)
    *(uint2*)&lds[tid * 8] = make_uint2(0u, 0u);

    // ---- W_hh A-frags for tile w: lane(q,r) holds A[m=r][k=8q+e + 32c]
    bf16x8 WH0, WH1, WH2, WH3, WL0, WL1, WL2, WL3;
    {
        const float* p = W_hh + (size_t)(16 * w + r) * HID + 8 * q;
        float4 fa, fb;
        fa = *(const float4*)(p +  0); fb = *(const float4*)(p +   4); SPLIT8(WH0, WL0, fa, fb);
        fa = *(const float4*)(p + 32); fb = *(const float4*)(p +  36); SPLIT8(WH1, WL1, fa, fb);
        fa = *(const float4*)(p + 64); fb = *(const float4*)(p +  68); SPLIT8(WH2, WL2, fa, fb);
        fa = *(const float4*)(p + 96); fb = *(const float4*)(p + 100); SPLIT8(WH3, WL3, fa, fb);
    }

    // ---- bias/x MFMA A'-frag (hoisted; only q==0 lanes nonzero)
    bf16x8 Ap;
    {
        const int jA = 16 * w + r;               // this lane's A-row j
        const float bias = b_ih[jA] + b_hh[jA];
        const float wih  = W_ih[jA];
        const float bm   = (q == 0) ? bias : 0.0f;
        const float wm   = (q == 0) ? wih  : 0.0f;
        const u32 w0 = cvt_pk_bf16(bm, wm);                       // e0,e1
        const float wl = wm - __uint_as_float(w0 & 0xffff0000u);
        const float bl = bm - __uint_as_float(w0 << 16);
        const u32 w1 = cvt_pk_bf16(wl, wm);                       // e2,e3
        const u32 w2 = cvt_pk_bf16(bl, 0.0f);                     // e4,e5
        Ap = frag_from(w0, w1, w2, 0u);
    }
    const float one_m  = (q == 0) ? 1.0f : 0.0f;
    const u32   bpw2   = cvt_pk_bf16(one_m, 0.0f);   // B' word2 (e4=1)

    // ---- per-lane C/D constants for epilogue (j0..j0+3 of this lane)
    const int j0 = 16 * w + 4 * q;

    // ---- slot-major LDS offsets (R16-verified)
    const int rswz  = ((r >> 3) << 4) ^ ((q & 1) << 5);
    const int roff0 = ((l * 16) ^ rswz);
    const int cw    = j0 >> 5;
    const int qw    = (j0 >> 3) & 3;
    const int woff  = cw * 1024 +
        ((((qw * 16 + r) * 16) + (j0 & 7) * 2) ^ ((r >> 3) << 4) ^ ((qw & 1) << 5));

    const float* __restrict__ xrow = x + (size_t)(b0 + r) * T_STEPS;
    float xt = xrow[0];
    f32x4 hv;

    __syncthreads();

#define STEP(RB, WB, TN) do {                                                 \
    const bf16x8 B0 = *(const bf16x8*)&lds[(RB) + roff0];                     \
    const bf16x8 B1 = *(const bf16x8*)&lds[(RB) + roff0 + 1024];              \
    const bf16x8 B2 = *(const bf16x8*)&lds[(RB) + roff0 + 2048];              \
    const bf16x8 B3 = *(const bf16x8*)&lds[(RB) + roff0 + 3072];              \
    const float xn = xrow[TN];                                                \
    /* B' build: [1, xhi | xhi, xlo | 1, 0 | 0] (q==0 lanes), ~5 VALU */      \
    const float xm   = (q == 0) ? xt : 0.0f;                                  \
    const u32   bw0  = cvt_pk_bf16(one_m, xm);                                \
    const float xhif = __uint_as_float(bw0 & 0xffff0000u);                    \
    const float xlo  = xm - xhif;                                             \
    const u32   bw1  = cvt_pk_bf16(xhif, xlo);                                \
    const bf16x8 Bp  = frag_from(bw0, bw1, bpw2, 0u);                         \
    /* TWO parallel chains: depth 5 (bias+WH) and 4 (WL) */                   \
    f32x4 acc0 = __builtin_amdgcn_mfma_f32_16x16x32_bf16(                     \
        Ap, Bp, (f32x4)(0.0f), 0, 0, 0);                                      \
    f32x4 acc1 = __builtin_amdgcn_mfma_f32_16x16x32_bf16(                     \
        WL0, B0, (f32x4)(0.0f), 0, 0, 0);                                     \
    MFMA(acc0, WH0, B0) MFMA(acc1, WL1, B1)                                   \
    MFMA(acc0, WH1, B1) MFMA(acc1, WL2, B2)                                   \
    MFMA(acc0, WH2, B2) MFMA(acc1, WL3, B3)                                   \
    MFMA(acc0, WH3, B3)                                                       \
    const f32x4 s = acc0 + acc1;                                              \
    hv[0] = tanh_fast(s[0]); hv[1] = tanh_fast(s[1]);                         \
    hv[2] = tanh_fast(s[2]); hv[3] = tanh_fast(s[3]);                         \
    *(uint2*)&lds[(WB) + woff] =                                              \
        make_uint2(cvt_pk_bf16(hv[0], hv[1]), cvt_pk_bf16(hv[2], hv[3]));     \
    xt = xn;                                                                  \
    __syncthreads();                                                          \
} while (0)

    for (int t = 0; t < T_STEPS; t += 2) {
        STEP(0,    4096, t + 1);
        STEP(4096, 0,    (t + 2 < T_STEPS) ? t + 2 : T_STEPS - 1);
    }
#undef STEP

    // ---- y[b0+r] = sum_j W_out[j] * h_last[j] + b_out
    const float4 wo = *(const float4*)(W_out + j0);
    float v = wo.x*hv[0] + wo.y*hv[1] + wo.z*hv[2] + wo.w*hv[3];
    v += __shfl_xor(v, 16, 64);
    v += __shfl_xor(v, 32, 64);          // lane r: sum over this tile's 16 j
    if (l < 16) *(float*)&lds[8192 + (w * 16 + r) * 4] = v;
    __syncthreads();
    if (tid < 16) {
        float s = 0.0f;
        #pragma unroll
        for (int ww = 0; ww < 8; ++ww)
            s += *(const float*)&lds[8192 + (ww * 16 + tid) * 4];
        y[b0 + tid] = s + b_out[0];
    }
}

extern "C" void kernel_launch(void* const* d_in, const int* in_sizes, int n_in,
                              void* d_out, int out_size, void* d_ws, size_t ws_size,
                              hipStream_t stream)
{
    const float* x     = (const float*)d_in[0];
    const float* W_ih  = (const float*)d_in[1];
    const float* W_hh  = (const float*)d_in[2];
    const float* b_ih  = (const float*)d_in[3];
    const float* b_hh  = (const float*)d_in[4];
    const float* W_out = (const float*)d_in[5];
    const float* b_out = (const float*)d_in[6];
    float* y = (float*)d_out;

    const int B = in_sizes[0] / T_STEPS;   // 1024
    rnn_diet2_kernel<<<B / ROWS, 512, 0, stream>>>(x, W_ih, W_hh, b_ih, b_hh,
                                                   W_out, b_out, y);
}

// Round 20
// 176.961 us; speedup vs baseline: 1.1244x; 1.1244x over previous
//
#include <hip/hip_runtime.h>

#define T_STEPS 512
#define HID 128
#define ROWS 16   // batch rows per block -> 64 blocks

typedef short bf16x8 __attribute__((ext_vector_type(8)));   // MFMA A/B frag
typedef float f32x4  __attribute__((ext_vector_type(4)));   // MFMA C/D frag
typedef unsigned int u32;
typedef u32 u32x4 __attribute__((ext_vector_type(4)));

// R18 numerics (164.5us) with HALVED wave count: 256 thr = 4 waves = 1/SIMD.
// Wave w owns j in [32w,32w+32) as TWO 16-j subtiles sharing the SAME 4
// B-frag ds_reads (B depends only on (q,r,chunk), not the wave). Rationale
// (R18 decomposition): LDS unit was serializing 32 ds_read_b128/step
// (~385cyc/CU, m134 12cyc each) and VALU 336cyc; halving waves halves LDS
// traffic and amortizes B'/loop VALU over 2 subtiles, MFMA issue unchanged.
// Per wave: 2 independent depth-9 MFMA chains (R19 proved VALU-merge of
// split chains is a loss; R18's single chain per 16-j output retained).

__device__ __forceinline__ u32 cvt_pk_bf16(float s0, float s1) {
    u32 d;  // d.lo = bf16(s0), d.hi = bf16(s1)
    asm("v_cvt_pk_bf16_f32 %0, %1, %2" : "=v"(d) : "v"(s0), "v"(s1));
    return d;
}
__device__ __forceinline__ bf16x8 frag_from(u32 a, u32 b, u32 c, u32 d) {
    u32x4 t = {a, b, c, d};
    return __builtin_bit_cast(bf16x8, t);
}
// tanh(a) = 1 - 2/(exp2(2a*log2e)+1); saturates correctly at +-inf
__device__ __forceinline__ float tanh_fast(float a) {
    const float e  = __builtin_amdgcn_exp2f(a * 2.885390081777926816f);
    const float rc = __builtin_amdgcn_rcpf(e + 1.0f);
    return fmaf(-2.0f, rc, 1.0f);
}

// split 8 f32 into hi/lo bf16 frags (W ~= WH + WL, residual ~2^-18 rel)
#define SPLIT8(HI, LO, fa, fb) do {                                           \
    u32 h0_ = cvt_pk_bf16(fa.x,fa.y), h1_ = cvt_pk_bf16(fa.z,fa.w);           \
    u32 h2_ = cvt_pk_bf16(fb.x,fb.y), h3_ = cvt_pk_bf16(fb.z,fb.w);           \
    float l0_ = fa.x - __uint_as_float(h0_ << 16);                            \
    float l1_ = fa.y - __uint_as_float(h0_ & 0xffff0000u);                    \
    float l2_ = fa.z - __uint_as_float(h1_ << 16);                            \
    float l3_ = fa.w - __uint_as_float(h1_ & 0xffff0000u);                    \
    float l4_ = fb.x - __uint_as_float(h2_ << 16);                            \
    float l5_ = fb.y - __uint_as_float(h2_ & 0xffff0000u);                    \
    float l6_ = fb.z - __uint_as_float(h3_ << 16);                            \
    float l7_ = fb.w - __uint_as_float(h3_ & 0xffff0000u);                    \
    u32 g0_ = cvt_pk_bf16(l0_,l1_), g1_ = cvt_pk_bf16(l2_,l3_);               \
    u32 g2_ = cvt_pk_bf16(l4_,l5_), g3_ = cvt_pk_bf16(l6_,l7_);               \
    HI = frag_from(h0_,h1_,h2_,h3_); LO = frag_from(g0_,g1_,g2_,g3_);         \
} while (0)

#define MFMA(ACC, A, B) \
    ACC = __builtin_amdgcn_mfma_f32_16x16x32_bf16(A, B, ACC, 0, 0, 0);

// LDS: h buf0 @0, h buf1 @4096 (slot-major, R16-verified); red @8192
#define LDS_BYTES (8192 + 256)

__global__ __launch_bounds__(256, 1)
__attribute__((amdgpu_waves_per_eu(1, 1)))
void rnn_w4_kernel(const float* __restrict__ x,
                   const float* __restrict__ W_ih,
                   const float* __restrict__ W_hh,
                   const float* __restrict__ b_ih,
                   const float* __restrict__ b_hh,
                   const float* __restrict__ W_out,
                   const float* __restrict__ b_out,
                   float* __restrict__ y)
{
    __shared__ __align__(16) char lds[LDS_BYTES];

    const int tid = threadIdx.x;
    const int w   = tid >> 6;        // wave 0..3: j in [32w, 32w+32)
    const int l   = tid & 63;
    const int q   = l >> 4;          // lane quarter (k-group / C row group)
    const int r   = l & 15;          // batch row (A row m / B col n / C col n)
    const int b0  = blockIdx.x * ROWS;

    // ---- zero h buf0 (4 KB, 256 threads x 16 B)
    {
        const u32x4 z = {0u, 0u, 0u, 0u};
        *(u32x4*)&lds[tid * 16] = z;
    }

    // ---- W_hh A-frags: subtile s rows j = 32w+16s+r, lane(q,r) k=8q+e+32c
    bf16x8 WH00, WH01, WH02, WH03, WL00, WL01, WL02, WL03;   // subtile 0
    bf16x8 WH10, WH11, WH12, WH13, WL10, WL11, WL12, WL13;   // subtile 1
    {
        const float* p = W_hh + (size_t)(32 * w + r) * HID + 8 * q;
        float4 fa, fb;
        fa = *(const float4*)(p +  0); fb = *(const float4*)(p +   4); SPLIT8(WH00, WL00, fa, fb);
        fa = *(const float4*)(p + 32); fb = *(const float4*)(p +  36); SPLIT8(WH01, WL01, fa, fb);
        fa = *(const float4*)(p + 64); fb = *(const float4*)(p +  68); SPLIT8(WH02, WL02, fa, fb);
        fa = *(const float4*)(p + 96); fb = *(const float4*)(p + 100); SPLIT8(WH03, WL03, fa, fb);
        p += (size_t)16 * HID;
        fa = *(const float4*)(p +  0); fb = *(const float4*)(p +   4); SPLIT8(WH10, WL10, fa, fb);
        fa = *(const float4*)(p + 32); fb = *(const float4*)(p +  36); SPLIT8(WH11, WL11, fa, fb);
        fa = *(const float4*)(p + 64); fb = *(const float4*)(p +  68); SPLIT8(WH12, WL12, fa, fb);
        fa = *(const float4*)(p + 96); fb = *(const float4*)(p + 100); SPLIT8(WH13, WL13, fa, fb);
    }

    // ---- bias/x MFMA A'-frags (hoisted; only q==0 lanes nonzero), per subtile
    bf16x8 Ap0, Ap1;
#define MAKE_AP(AP, JA) do {                                                  \
    const float bias_ = b_ih[JA] + b_hh[JA];                                  \
    const float wih_  = W_ih[JA];                                             \
    const float bm_   = (q == 0) ? bias_ : 0.0f;                              \
    const float wm_   = (q == 0) ? wih_  : 0.0f;                              \
    const u32 w0_ = cvt_pk_bf16(bm_, wm_);                                    \
    const float wl_ = wm_ - __uint_as_float(w0_ & 0xffff0000u);               \
    const float bl_ = bm_ - __uint_as_float(w0_ << 16);                       \
    const u32 w1_ = cvt_pk_bf16(wl_, wm_);                                    \
    const u32 w2_ = cvt_pk_bf16(bl_, 0.0f);                                   \
    AP = frag_from(w0_, w1_, w2_, 0u);                                        \
} while (0)
    MAKE_AP(Ap0, 32 * w + r);
    MAKE_AP(Ap1, 32 * w + 16 + r);
#undef MAKE_AP
    const float one_m = (q == 0) ? 1.0f : 0.0f;
    const u32   bpw2  = cvt_pk_bf16(one_m, 0.0f);   // B' word2 (e4=1)

    // ---- per-lane epilogue j bases
    const int j00 = 32 * w + 4 * q;          // subtile 0
    const int j01 = 32 * w + 16 + 4 * q;     // subtile 1

    // ---- slot-major LDS offsets (R16-verified)
    const int rswz  = ((r >> 3) << 4) ^ ((q & 1) << 5);
    const int roff0 = ((l * 16) ^ rswz);
#define WOFF(J0) ((J0 >> 5) * 1024 +                                          \
    (((((J0 >> 3) & 3) * 16 + r) * 16 + (J0 & 7) * 2)                         \
     ^ ((r >> 3) << 4) ^ (((J0 >> 3) & 1) << 5)))
    const int woff0 = WOFF(j00);
    const int woff1 = WOFF(j01);
#undef WOFF

    const float* __restrict__ xrow = x + (size_t)(b0 + r) * T_STEPS;
    float xt = xrow[0];
    f32x4 hv0, hv1;

    __syncthreads();

#define STEP(RB, WB, TN) do {                                                 \
    const bf16x8 B0 = *(const bf16x8*)&lds[(RB) + roff0];                     \
    const bf16x8 B1 = *(const bf16x8*)&lds[(RB) + roff0 + 1024];              \
    const bf16x8 B2 = *(const bf16x8*)&lds[(RB) + roff0 + 2048];              \
    const bf16x8 B3 = *(const bf16x8*)&lds[(RB) + roff0 + 3072];              \
    const float xn = xrow[TN];                                                \
    /* B' build (SHARED by both subtiles): [1,xhi | xhi,xlo | 1,0 | 0] */     \
    const float xm   = (q == 0) ? xt : 0.0f;                                  \
    const u32   bw0  = cvt_pk_bf16(one_m, xm);                                \
    const float xhif = __uint_as_float(bw0 & 0xffff0000u);                    \
    const float xlo  = xm - xhif;                                             \
    const u32   bw1  = cvt_pk_bf16(xhif, xlo);                                \
    const bf16x8 Bp  = frag_from(bw0, bw1, bpw2, 0u);                         \
    /* two INDEPENDENT depth-9 chains, interleaved issue */                   \
    f32x4 acc0 = __builtin_amdgcn_mfma_f32_16x16x32_bf16(                     \
        Ap0, Bp, (f32x4)(0.0f), 0, 0, 0);                                     \
    f32x4 acc1 = __builtin_amdgcn_mfma_f32_16x16x32_bf16(                     \
        Ap1, Bp, (f32x4)(0.0f), 0, 0, 0);                                     \
    MFMA(acc0, WH00, B0) MFMA(acc1, WH10, B0)                                 \
    MFMA(acc0, WH01, B1) MFMA(acc1, WH11, B1)                                 \
    MFMA(acc0, WH02, B2) MFMA(acc1, WH12, B2)                                 \
    MFMA(acc0, WH03, B3) MFMA(acc1, WH13, B3)                                 \
    MFMA(acc0, WL00, B0) MFMA(acc1, WL10, B0)                                 \
    MFMA(acc0, WL01, B1) MFMA(acc1, WL11, B1)                                 \
    MFMA(acc0, WL02, B2) MFMA(acc1, WL12, B2)                                 \
    MFMA(acc0, WL03, B3) MFMA(acc1, WL13, B3)                                 \
    hv0[0] = tanh_fast(acc0[0]); hv0[1] = tanh_fast(acc0[1]);                 \
    hv0[2] = tanh_fast(acc0[2]); hv0[3] = tanh_fast(acc0[3]);                 \
    hv1[0] = tanh_fast(acc1[0]); hv1[1] = tanh_fast(acc1[1]);                 \
    hv1[2] = tanh_fast(acc1[2]); hv1[3] = tanh_fast(acc1[3]);                 \
    *(uint2*)&lds[(WB) + woff0] =                                             \
        make_uint2(cvt_pk_bf16(hv0[0], hv0[1]), cvt_pk_bf16(hv0[2], hv0[3])); \
    *(uint2*)&lds[(WB) + woff1] =                                             \
        make_uint2(cvt_pk_bf16(hv1[0], hv1[1]), cvt_pk_bf16(hv1[2], hv1[3])); \
    xt = xn;                                                                  \
    __syncthreads();                                                          \
} while (0)

    for (int t = 0; t < T_STEPS; t += 2) {
        STEP(0,    4096, t + 1);
        STEP(4096, 0,    (t + 2 < T_STEPS) ? t + 2 : T_STEPS - 1);
    }
#undef STEP

    // ---- y[b0+r] = sum_j W_out[j] * h_last[j] + b_out
    const float4 wo0 = *(const float4*)(W_out + j00);
    const float4 wo1 = *(const float4*)(W_out + j01);
    float v = wo0.x*hv0[0] + wo0.y*hv0[1] + wo0.z*hv0[2] + wo0.w*hv0[3]
            + wo1.x*hv1[0] + wo1.y*hv1[1] + wo1.z*hv1[2] + wo1.w*hv1[3];
    v += __shfl_xor(v, 16, 64);
    v += __shfl_xor(v, 32, 64);          // lane r: sum over this wave's 32 j
    if (l < 16) *(float*)&lds[8192 + (w * 16 + r) * 4] = v;
    __syncthreads();
    if (tid < 16) {
        const float s = *(const float*)&lds[8192 + tid * 4]
                      + *(const float*)&lds[8192 + 64  + tid * 4]
                      + *(const float*)&lds[8192 + 128 + tid * 4]
                      + *(const float*)&lds[8192 + 192 + tid * 4];
        y[b0 + tid] = s + b_out[0];
    }
}

extern "C" void kernel_launch(void* const* d_in, const int* in_sizes, int n_in,
                              void* d_out, int out_size, void* d_ws, size_t ws_size,
                              hipStream_t stream)
{
    const float* x     = (const float*)d_in[0];
    const float* W_ih  = (const float*)d_in[1];
    const float* W_hh  = (const float*)d_in[2];
    const float* b_ih  = (const float*)d_in[3];
    const float* b_hh  = (const float*)d_in[4];
    const float* W_out = (const float*)d_in[5];
    const float* b_out = (const float*)d_in[6];
    float* y = (float*)d_out;

    const int B = in_sizes[0] / T_STEPS;   // 1024
    rnn_w4_kernel<<<B / ROWS, 256, 0, stream>>>(x, W_ih, W_hh, b_ih, b_hh,
                                                W_out, b_out, y);
}

// Round 21
// 148.717 us; speedup vs baseline: 1.3380x; 1.1899x over previous
//
#include <hip/hip_runtime.h>

#define T_STEPS 512
#define HID 128
#define ROWS 16   // batch rows per block -> 64 blocks
#define SCALE 2.885390081777926816f   // 2*log2(e): pre-scales W so tanh uses exp2 directly

typedef short bf16x8 __attribute__((ext_vector_type(8)));   // MFMA A/B frag
typedef float f32x4  __attribute__((ext_vector_type(4)));   // MFMA C/D frag
typedef unsigned int u32;
typedef u32 u32x4 __attribute__((ext_vector_type(4)));

// R18 (164.5us) + VALU strip-down:
// (1) W_hh/W_ih/bias pre-scaled by 2log2e -> tanh = 1-2*rcp(exp2(acc)+1),
//     no per-element multiply.
// (2) B' x-words precomputed for ALL 512 steps into a 64KB LDS table
//     (one-time pre-pass). Per step: ONE ds_read_b64 via per-lane stride
//     pointer (q!=0 lanes read a zero entry; same-addr = broadcast, free).
//     Replaces the per-step B' build + global x load + clamp bookkeeping.
// Loop body: 4 ds_read_b128 + 1 ds_read_b64 + 9-chain MFMA + 16-instr tanh
// + 2 cvt_pk + ds_write_b64 + barrier  (~25 VALU/wave/step vs R18's ~84).

// LDS map: 0 h buf0 | 4096 h buf1 (slot-major, R16-verified)
//          8192 xw table [t][r] uint2 (64KB) | 73728 zero pad | 73744 red
#define XW_OFF   8192
#define Z_OFF    73728
#define RED_OFF  73744
#define LDS_BYTES (73744 + 512)

__device__ __forceinline__ u32 cvt_pk_bf16(float s0, float s1) {
    u32 d;  // d.lo = bf16(s0), d.hi = bf16(s1)
    asm("v_cvt_pk_bf16_f32 %0, %1, %2" : "=v"(d) : "v"(s0), "v"(s1));
    return d;
}
__device__ __forceinline__ bf16x8 frag_from(u32 a, u32 b, u32 c, u32 d) {
    u32x4 t = {a, b, c, d};
    return __builtin_bit_cast(bf16x8, t);
}

// split 8 f32 into hi/lo bf16 frags (W ~= WH + WL, residual ~2^-18 rel)
#define SPLIT8(HI, LO, fa, fb) do {                                           \
    u32 h0_ = cvt_pk_bf16(fa.x,fa.y), h1_ = cvt_pk_bf16(fa.z,fa.w);           \
    u32 h2_ = cvt_pk_bf16(fb.x,fb.y), h3_ = cvt_pk_bf16(fb.z,fb.w);           \
    float l0_ = fa.x - __uint_as_float(h0_ << 16);                            \
    float l1_ = fa.y - __uint_as_float(h0_ & 0xffff0000u);                    \
    float l2_ = fa.z - __uint_as_float(h1_ << 16);                            \
    float l3_ = fa.w - __uint_as_float(h1_ & 0xffff0000u);                    \
    float l4_ = fb.x - __uint_as_float(h2_ << 16);                            \
    float l5_ = fb.y - __uint_as_float(h2_ & 0xffff0000u);                    \
    float l6_ = fb.z - __uint_as_float(h3_ << 16);                            \
    float l7_ = fb.w - __uint_as_float(h3_ & 0xffff0000u);                    \
    u32 g0_ = cvt_pk_bf16(l0_,l1_), g1_ = cvt_pk_bf16(l2_,l3_);               \
    u32 g2_ = cvt_pk_bf16(l4_,l5_), g3_ = cvt_pk_bf16(l6_,l7_);               \
    HI = frag_from(h0_,h1_,h2_,h3_); LO = frag_from(g0_,g1_,g2_,g3_);         \
} while (0)

#define MFMA(ACC, A, B) \
    ACC = __builtin_amdgcn_mfma_f32_16x16x32_bf16(A, B, ACC, 0, 0, 0);

__global__ __launch_bounds__(512, 1)
__attribute__((amdgpu_waves_per_eu(2, 2)))
void rnn_lean_kernel(const float* __restrict__ x,
                     const float* __restrict__ W_ih,
                     const float* __restrict__ W_hh,
                     const float* __restrict__ b_ih,
                     const float* __restrict__ b_hh,
                     const float* __restrict__ W_out,
                     const float* __restrict__ b_out,
                     float* __restrict__ y)
{
    __shared__ __align__(16) char lds[LDS_BYTES];

    const int tid = threadIdx.x;
    const int w   = tid >> 6;        // wave 0..7: j-tile [16w, 16w+16)
    const int l   = tid & 63;
    const int q   = l >> 4;          // lane quarter (k-group / C row group)
    const int r   = l & 15;          // batch row (A row m / B col n / C col n)
    const int b0  = blockIdx.x * ROWS;

    // ---- zero h buf0 (4 KB)
    *(uint2*)&lds[tid * 8] = make_uint2(0u, 0u);
    if (tid == 0) *(uint2*)&lds[Z_OFF] = make_uint2(0u, 0u);

    // ---- pre-pass: xw[t][r] = {bw0, bw1} for the whole sequence (64 KB)
    // bw0 = pk(bf16(1), bf16(x)); bw1 = pk(bf16(xhi), bf16(x - xhi))
    for (int i = tid; i < ROWS * T_STEPS; i += 512) {
        const int rr = i >> 9;           // coalesced: consecutive tid -> consecutive t
        const int tt = i & 511;
        const float xv = x[(size_t)(b0 + rr) * T_STEPS + tt];
        const u32 w0 = cvt_pk_bf16(1.0f, xv);
        const float xh = __uint_as_float(w0 & 0xffff0000u);
        const u32 w1 = cvt_pk_bf16(xh, xv - xh);
        *(uint2*)&lds[XW_OFF + (tt * 16 + rr) * 8] = make_uint2(w0, w1);
    }

    // ---- W_hh A-frags (PRE-SCALED by 2log2e): lane(q,r) k=8q+e+32c
    bf16x8 WH0, WH1, WH2, WH3, WL0, WL1, WL2, WL3;
    {
        const float* p = W_hh + (size_t)(16 * w + r) * HID + 8 * q;
        float4 fa, fb;
#define LD4S(D, P) { float4 t_ = *(const float4*)(P);                          \
    D.x = t_.x*SCALE; D.y = t_.y*SCALE; D.z = t_.z*SCALE; D.w = t_.w*SCALE; }
        LD4S(fa, p +  0) LD4S(fb, p +   4) SPLIT8(WH0, WL0, fa, fb);
        LD4S(fa, p + 32) LD4S(fb, p +  36) SPLIT8(WH1, WL1, fa, fb);
        LD4S(fa, p + 64) LD4S(fb, p +  68) SPLIT8(WH2, WL2, fa, fb);
        LD4S(fa, p + 96) LD4S(fb, p + 100) SPLIT8(WH3, WL3, fa, fb);
#undef LD4S
    }

    // ---- bias/x MFMA A'-frag (scaled; only q==0 lanes nonzero)
    bf16x8 Ap;
    {
        const int jA = 16 * w + r;
        const float bias = (b_ih[jA] + b_hh[jA]) * SCALE;
        const float wih  = W_ih[jA] * SCALE;
        const float bm   = (q == 0) ? bias : 0.0f;
        const float wm   = (q == 0) ? wih  : 0.0f;
        const u32 w0 = cvt_pk_bf16(bm, wm);                       // e0,e1
        const float wl = wm - __uint_as_float(w0 & 0xffff0000u);
        const float bl = bm - __uint_as_float(w0 << 16);
        const u32 w1 = cvt_pk_bf16(wl, wm);                       // e2,e3
        const u32 w2 = cvt_pk_bf16(bl, 0.0f);                     // e4,e5
        Ap = frag_from(w0, w1, w2, 0u);
    }
    const u32 bpw2 = cvt_pk_bf16((q == 0) ? 1.0f : 0.0f, 0.0f);   // B' word2

    const int j0 = 16 * w + 4 * q;

    // ---- slot-major LDS offsets (R16-verified)
    const int rswz  = ((r >> 3) << 4) ^ ((q & 1) << 5);
    const int roff0 = ((l * 16) ^ rswz);
    const int cw    = j0 >> 5;
    const int qw    = (j0 >> 3) & 3;
    const int woff  = cw * 1024 +
        ((((qw * 16 + r) * 16) + (j0 & 7) * 2) ^ ((r >> 3) << 4) ^ ((qw & 1) << 5));

    // ---- xw stream pointer: q==0 lanes walk the table, others read zeros
    u32 xaddr        = (q == 0) ? (u32)(XW_OFF + r * 8) : (u32)Z_OFF;
    const u32 xstride = (q == 0) ? 128u : 0u;

    f32x4 hv;
    __syncthreads();

#define STEP(RB, WB) do {                                                     \
    const bf16x8 B0 = *(const bf16x8*)&lds[(RB) + roff0];                     \
    const bf16x8 B1 = *(const bf16x8*)&lds[(RB) + roff0 + 1024];              \
    const bf16x8 B2 = *(const bf16x8*)&lds[(RB) + roff0 + 2048];              \
    const bf16x8 B3 = *(const bf16x8*)&lds[(RB) + roff0 + 3072];              \
    const uint2 bw  = *(const uint2*)&lds[xaddr];                             \
    const bf16x8 Bp = frag_from(bw.x, bw.y, bpw2, 0u);                        \
    f32x4 acc = __builtin_amdgcn_mfma_f32_16x16x32_bf16(                      \
        Ap, Bp, (f32x4)(0.0f), 0, 0, 0);                                      \
    MFMA(acc, WH0, B0) MFMA(acc, WH1, B1)                                     \
    MFMA(acc, WH2, B2) MFMA(acc, WH3, B3)                                     \
    MFMA(acc, WL0, B0) MFMA(acc, WL1, B1)                                     \
    MFMA(acc, WL2, B2) MFMA(acc, WL3, B3)                                     \
    const float e0 = __builtin_amdgcn_exp2f(acc[0]);                          \
    const float e1 = __builtin_amdgcn_exp2f(acc[1]);                          \
    const float e2 = __builtin_amdgcn_exp2f(acc[2]);                          \
    const float e3 = __builtin_amdgcn_exp2f(acc[3]);                          \
    const float rc0 = __builtin_amdgcn_rcpf(e0 + 1.0f);                       \
    const float rc1 = __builtin_amdgcn_rcpf(e1 + 1.0f);                       \
    const float rc2 = __builtin_amdgcn_rcpf(e2 + 1.0f);                       \
    const float rc3 = __builtin_amdgcn_rcpf(e3 + 1.0f);                       \
    hv[0] = fmaf(-2.0f, rc0, 1.0f); hv[1] = fmaf(-2.0f, rc1, 1.0f);           \
    hv[2] = fmaf(-2.0f, rc2, 1.0f); hv[3] = fmaf(-2.0f, rc3, 1.0f);           \
    *(uint2*)&lds[(WB) + woff] =                                              \
        make_uint2(cvt_pk_bf16(hv[0], hv[1]), cvt_pk_bf16(hv[2], hv[3]));     \
    xaddr += xstride;                                                         \
    __syncthreads();                                                          \
} while (0)

    for (int t = 0; t < T_STEPS; t += 2) {
        STEP(0,    4096);
        STEP(4096, 0);
    }
#undef STEP

    // ---- y[b0+r] = sum_j W_out[j] * h_last[j] + b_out
    const float4 wo = *(const float4*)(W_out + j0);
    float v = wo.x*hv[0] + wo.y*hv[1] + wo.z*hv[2] + wo.w*hv[3];
    v += __shfl_xor(v, 16, 64);
    v += __shfl_xor(v, 32, 64);          // lane r: sum over this tile's 16 j
    if (l < 16) *(float*)&lds[RED_OFF + (w * 16 + r) * 4] = v;
    __syncthreads();
    if (tid < 16) {
        float s = 0.0f;
        #pragma unroll
        for (int ww = 0; ww < 8; ++ww)
            s += *(const float*)&lds[RED_OFF + (ww * 16 + tid) * 4];
        y[b0 + tid] = s + b_out[0];
    }
}

extern "C" void kernel_launch(void* const* d_in, const int* in_sizes, int n_in,
                              void* d_out, int out_size, void* d_ws, size_t ws_size,
                              hipStream_t stream)
{
    const float* x     = (const float*)d_in[0];
    const float* W_ih  = (const float*)d_in[1];
    const float* W_hh  = (const float*)d_in[2];
    const float* b_ih  = (const float*)d_in[3];
    const float* b_hh  = (const float*)d_in[4];
    const float* W_out = (const float*)d_in[5];
    const float* b_out = (const float*)d_in[6];
    float* y = (float*)d_out;

    const int B = in_sizes[0] / T_STEPS;   // 1024
    rnn_lean_kernel<<<B / ROWS, 512, 0, stream>>>(x, W_ih, W_hh, b_ih, b_hh,
                                                  W_out, b_out, y);
}

// Round 22
// 134.654 us; speedup vs baseline: 1.4777x; 1.1044x over previous
//
#include <hip/hip_runtime.h>

#define T_STEPS 512
#define HID 128
#define ROWS 16   // batch rows per block -> 64 blocks
#define SCALE 2.885390081777926816f   // 2*log2(e): pre-scales W so tanh uses exp2 directly

typedef short bf16x8 __attribute__((ext_vector_type(8)));   // MFMA A/B frag
typedef float f32x4  __attribute__((ext_vector_type(4)));   // MFMA C/D frag
typedef unsigned int u32;
typedef u32 u32x4 __attribute__((ext_vector_type(4)));

// R21 (148.7us) + ONE change: W_hh kept as PLAIN bf16 (no WL residual term).
// Error budget: h is already bf16 (2^-9 rel/step, R8: 3.9e-3 final); W-quant
// adds a same-magnitude per-step term -> predicted final absmax 4-9e-3 < 1e-2.
// Payoff: MFMA chain depth 9 -> 5 (~270 -> ~150 cyc critical path), 5 MFMA
// issued/wave/step instead of 9.

// LDS map: 0 h buf0 | 4096 h buf1 (slot-major, R16-verified)
//          8192 xw table [t][r] uint2 (64KB) | 73728 zero pad | 73744 red
#define XW_OFF   8192
#define Z_OFF    73728
#define RED_OFF  73744
#define LDS_BYTES (73744 + 512)

__device__ __forceinline__ u32 cvt_pk_bf16(float s0, float s1) {
    u32 d;  // d.lo = bf16(s0), d.hi = bf16(s1)
    asm("v_cvt_pk_bf16_f32 %0, %1, %2" : "=v"(d) : "v"(s0), "v"(s1));
    return d;
}
__device__ __forceinline__ bf16x8 frag_from(u32 a, u32 b, u32 c, u32 d) {
    u32x4 t = {a, b, c, d};
    return __builtin_bit_cast(bf16x8, t);
}

#define MFMA(ACC, A, B) \
    ACC = __builtin_amdgcn_mfma_f32_16x16x32_bf16(A, B, ACC, 0, 0, 0);

__global__ __launch_bounds__(512, 1)
__attribute__((amdgpu_waves_per_eu(2, 2)))
void rnn_lean5_kernel(const float* __restrict__ x,
                      const float* __restrict__ W_ih,
                      const float* __restrict__ W_hh,
                      const float* __restrict__ b_ih,
                      const float* __restrict__ b_hh,
                      const float* __restrict__ W_out,
                      const float* __restrict__ b_out,
                      float* __restrict__ y)
{
    __shared__ __align__(16) char lds[LDS_BYTES];

    const int tid = threadIdx.x;
    const int w   = tid >> 6;        // wave 0..7: j-tile [16w, 16w+16)
    const int l   = tid & 63;
    const int q   = l >> 4;          // lane quarter (k-group / C row group)
    const int r   = l & 15;          // batch row (A row m / B col n / C col n)
    const int b0  = blockIdx.x * ROWS;

    // ---- zero h buf0 (4 KB)
    *(uint2*)&lds[tid * 8] = make_uint2(0u, 0u);
    if (tid == 0) *(uint2*)&lds[Z_OFF] = make_uint2(0u, 0u);

    // ---- pre-pass: xw[t][r] = {bw0, bw1} for the whole sequence (64 KB)
    // bw0 = pk(bf16(1), bf16(x)); bw1 = pk(bf16(xhi), bf16(x - xhi))
    for (int i = tid; i < ROWS * T_STEPS; i += 512) {
        const int rr = i >> 9;           // coalesced: consecutive tid -> consecutive t
        const int tt = i & 511;
        const float xv = x[(size_t)(b0 + rr) * T_STEPS + tt];
        const u32 w0 = cvt_pk_bf16(1.0f, xv);
        const float xh = __uint_as_float(w0 & 0xffff0000u);
        const u32 w1 = cvt_pk_bf16(xh, xv - xh);
        *(uint2*)&lds[XW_OFF + (tt * 16 + rr) * 8] = make_uint2(w0, w1);
    }

    // ---- W_hh A-frags, plain bf16, PRE-SCALED by 2log2e: lane(q,r) k=8q+e+32c
    bf16x8 WH0, WH1, WH2, WH3;
    {
        const float* p = W_hh + (size_t)(16 * w + r) * HID + 8 * q;
#define LDW(DST, OFF) do {                                                    \
    float4 fa_ = *(const float4*)(p + (OFF));                                 \
    float4 fb_ = *(const float4*)(p + (OFF) + 4);                             \
    DST = frag_from(cvt_pk_bf16(fa_.x*SCALE, fa_.y*SCALE),                    \
                    cvt_pk_bf16(fa_.z*SCALE, fa_.w*SCALE),                    \
                    cvt_pk_bf16(fb_.x*SCALE, fb_.y*SCALE),                    \
                    cvt_pk_bf16(fb_.z*SCALE, fb_.w*SCALE));                   \
} while (0)
        LDW(WH0,  0); LDW(WH1, 32); LDW(WH2, 64); LDW(WH3, 96);
#undef LDW
    }

    // ---- bias/x MFMA A'-frag (scaled; only q==0 lanes nonzero)
    bf16x8 Ap;
    {
        const int jA = 16 * w + r;
        const float bias = (b_ih[jA] + b_hh[jA]) * SCALE;
        const float wih  = W_ih[jA] * SCALE;
        const float bm   = (q == 0) ? bias : 0.0f;
        const float wm   = (q == 0) ? wih  : 0.0f;
        const u32 w0 = cvt_pk_bf16(bm, wm);                       // e0,e1
        const float wl = wm - __uint_as_float(w0 & 0xffff0000u);
        const float bl = bm - __uint_as_float(w0 << 16);
        const u32 w1 = cvt_pk_bf16(wl, wm);                       // e2,e3
        const u32 w2 = cvt_pk_bf16(bl, 0.0f);                     // e4,e5
        Ap = frag_from(w0, w1, w2, 0u);
    }
    const u32 bpw2 = cvt_pk_bf16((q == 0) ? 1.0f : 0.0f, 0.0f);   // B' word2

    const int j0 = 16 * w + 4 * q;

    // ---- slot-major LDS offsets (R16-verified)
    const int rswz  = ((r >> 3) << 4) ^ ((q & 1) << 5);
    const int roff0 = ((l * 16) ^ rswz);
    const int cw    = j0 >> 5;
    const int qw    = (j0 >> 3) & 3;
    const int woff  = cw * 1024 +
        ((((qw * 16 + r) * 16) + (j0 & 7) * 2) ^ ((r >> 3) << 4) ^ ((qw & 1) << 5));

    // ---- xw stream pointer: q==0 lanes walk the table, others read zeros
    u32 xaddr        = (q == 0) ? (u32)(XW_OFF + r * 8) : (u32)Z_OFF;
    const u32 xstride = (q == 0) ? 128u : 0u;

    f32x4 hv;
    __syncthreads();

#define STEP(RB, WB) do {                                                     \
    const bf16x8 B0 = *(const bf16x8*)&lds[(RB) + roff0];                     \
    const bf16x8 B1 = *(const bf16x8*)&lds[(RB) + roff0 + 1024];              \
    const bf16x8 B2 = *(const bf16x8*)&lds[(RB) + roff0 + 2048];              \
    const bf16x8 B3 = *(const bf16x8*)&lds[(RB) + roff0 + 3072];              \
    const uint2 bw  = *(const uint2*)&lds[xaddr];                             \
    const bf16x8 Bp = frag_from(bw.x, bw.y, bpw2, 0u);                        \
    f32x4 acc = __builtin_amdgcn_mfma_f32_16x16x32_bf16(                      \
        Ap, Bp, (f32x4)(0.0f), 0, 0, 0);                                      \
    MFMA(acc, WH0, B0) MFMA(acc, WH1, B1)                                     \
    MFMA(acc, WH2, B2) MFMA(acc, WH3, B3)                                     \
    const float e0 = __builtin_amdgcn_exp2f(acc[0]);                          \
    const float e1 = __builtin_amdgcn_exp2f(acc[1]);                          \
    const float e2 = __builtin_amdgcn_exp2f(acc[2]);                          \
    const float e3 = __builtin_amdgcn_exp2f(acc[3]);                          \
    const float rc0 = __builtin_amdgcn_rcpf(e0 + 1.0f);                       \
    const float rc1 = __builtin_amdgcn_rcpf(e1 + 1.0f);                       \
    const float rc2 = __builtin_amdgcn_rcpf(e2 + 1.0f);                       \
    const float rc3 = __builtin_amdgcn_rcpf(e3 + 1.0f);                       \
    hv[0] = fmaf(-2.0f, rc0, 1.0f); hv[1] = fmaf(-2.0f, rc1, 1.0f);           \
    hv[2] = fmaf(-2.0f, rc2, 1.0f); hv[3] = fmaf(-2.0f, rc3, 1.0f);           \
    *(uint2*)&lds[(WB) + woff] =                                              \
        make_uint2(cvt_pk_bf16(hv[0], hv[1]), cvt_pk_bf16(hv[2], hv[3]));     \
    xaddr += xstride;                                                         \
    __syncthreads();                                                          \
} while (0)

    for (int t = 0; t < T_STEPS; t += 2) {
        STEP(0,    4096);
        STEP(4096, 0);
    }
#undef STEP

    // ---- y[b0+r] = sum_j W_out[j] * h_last[j] + b_out
    const float4 wo = *(const float4*)(W_out + j0);
    float v = wo.x*hv[0] + wo.y*hv[1] + wo.z*hv[2] + wo.w*hv[3];
    v += __shfl_xor(v, 16, 64);
    v += __shfl_xor(v, 32, 64);          // lane r: sum over this tile's 16 j
    if (l < 16) *(float*)&lds[RED_OFF + (w * 16 + r) * 4] = v;
    __syncthreads();
    if (tid < 16) {
        float s = 0.0f;
        #pragma unroll
        for (int ww = 0; ww < 8; ++ww)
            s += *(const float*)&lds[RED_OFF + (ww * 16 + tid) * 4];
        y[b0 + tid] = s + b_out[0];
    }
}

extern "C" void kernel_launch(void* const* d_in, const int* in_sizes, int n_in,
                              void* d_out, int out_size, void* d_ws, size_t ws_size,
                              hipStream_t stream)
{
    const float* x     = (const float*)d_in[0];
    const float* W_ih  = (const float*)d_in[1];
    const float* W_hh  = (const float*)d_in[2];
    const float* b_ih  = (const float*)d_in[3];
    const float* b_hh  = (const float*)d_in[4];
    const float* W_out = (const float*)d_in[5];
    const float* b_out = (const float*)d_in[6];
    float* y = (float*)d_out;

    const int B = in_sizes[0] / T_STEPS;   // 1024
    rnn_lean5_kernel<<<B / ROWS, 512, 0, stream>>>(x, W_ih, W_hh, b_ih, b_hh,
                                                   W_out, b_out, y);
}